// Round 3
// baseline (556.580 us; speedup 1.0000x reference)
//
#include <hip/hip_runtime.h>
#include <hip/hip_bf16.h>
#include <math.h>

#define N_NODES 100000
#define N_PAD 100032   // padded row count for workspace feature buffers
#define N_EDGES 1600000
#define HID 128
#define N_CLASS 10

#define NR2 256
#define RANGE2 391      // 256*391 = 100096 >= N_NODES
#define CAST_ITEMS (N_NODES * (HID / 4))   // 3.2M float4 units
#define CAST_BLOCKS ((CAST_ITEMS + 2047) / 2048)  // 1563
#define WSPLIT_BLOCKS 384                  // 6*16384/256
#define EHIST_BLOCKS 1563                  // 1563*1024 >= 1.6M edges

typedef float f32x4 __attribute__((ext_vector_type(4)));
typedef short short8 __attribute__((ext_vector_type(8)));
typedef unsigned short us4 __attribute__((ext_vector_type(4)));

// bf16 helpers (round-to-nearest-even)
__device__ __forceinline__ unsigned short f2bf(float x) {
    unsigned u = __float_as_uint(x);
    unsigned r = u + 0x7FFF + ((u >> 16) & 1);
    return (unsigned short)(r >> 16);
}
__device__ __forceinline__ float bf2f(unsigned short h) {
    return __uint_as_float(((unsigned)h) << 16);
}
__device__ __forceinline__ float elu(float x) {
    return x > 0.f ? x : (expf(x) - 1.f);
}
__device__ __forceinline__ float4 us4f(us4 v) {
    float4 o;
    o.x = bf2f(v.x); o.y = bf2f(v.y); o.z = bf2f(v.z); o.w = bf2f(v.w);
    return o;
}

// ---------------------------------------------------------------------------
// setup_k: fused degree-histogram + x-cast + weight-pack (block-range dispatch).
//   blocks [0,1563): atomicAdd deg[dst] over all edges
//   blocks [1563,3126): fp32->bf16 cast of x
//   blocks [3126,3510): MLP weight pack to B-frag layout
//   block 3510: fcW pack
// deg must be zeroed before this kernel (hipMemsetAsync).
// ---------------------------------------------------------------------------
__global__ __launch_bounds__(256) void setup_k(
    const int* __restrict__ dst, int* __restrict__ deg,
    const float* __restrict__ x, unsigned short* __restrict__ hb,
    const float* __restrict__ Wa, const float* __restrict__ Wb,
    unsigned short* __restrict__ Whp,
    const float* __restrict__ fcW, unsigned short* __restrict__ fcWph) {
    const int b = blockIdx.x;
    const int tid = threadIdx.x;

    if (b < EHIST_BLOCKS) {
        // ---- degree histogram ----
#pragma unroll
        for (int it = 0; it < 4; it++) {
            int i = b * 1024 + it * 256 + tid;
            if (i < N_EDGES) atomicAdd(&deg[dst[i]], 1);
        }
    } else if (b < EHIST_BLOCKS + CAST_BLOCKS) {
        // ---- x cast ----
        const int cb = b - EHIST_BLOCKS;
#pragma unroll
        for (int it = 0; it < 8; it++) {
            int i = cb * 2048 + it * 256 + tid;
            if (i < CAST_ITEMS) {
                float4 v = ((const float4*)x)[i];
                us4 o = {f2bf(v.x), f2bf(v.y), f2bf(v.z), f2bf(v.w)};
                ((us4*)hb)[i] = o;
            }
        }
    } else if (b < EHIST_BLOCKS + CAST_BLOCKS + WSPLIT_BLOCKS) {
        // ---- MLP weight pack ----
        int f = (b - EHIST_BLOCKS - CAST_BLOCKS) * 256 + tid;  // < 98304
        int g = f >> 14;
        int r = f & 16383;
        int j = r & 7;
        int L = (r >> 3) & 63;
        int t = r >> 9;
        int kb = t >> 3, nt = t & 7;
        int k = kb * 32 + ((L >> 4) & 3) * 8 + j;
        int n = nt * 16 + (L & 15);
        int layer = g >> 1;
        const float* W = (g & 1) ? Wb : Wa;
        Whp[f] = f2bf(W[layer * 16384 + k * 128 + n]);
    } else {
        // ---- fcW pack ----
#pragma unroll
        for (int it = 0; it < 8; it++) {
            int f = it * 256 + tid;  // < 2048
            int j = f & 7;
            int L = (f >> 3) & 63;
            int kb = f >> 9;
            int k = kb * 32 + ((L >> 4) & 3) * 8 + j;
            int n = L & 15;
            fcWph[f] = f2bf((n < N_CLASS) ? fcW[k * N_CLASS + n] : 0.f);
        }
    }
}

// ---------------------------------------------------------------------------
// scanA_k: per-range degree sums (256 ranges of 391 nodes).
// ---------------------------------------------------------------------------
__global__ __launch_bounds__(256) void scanA_k(const int* __restrict__ deg,
                                               int* __restrict__ rsum) {
    __shared__ int s[256];
    const int q = blockIdx.x;
    const int tid = threadIdx.x;
    const int n0 = q * RANGE2;
    int v = 0;
    for (int i = tid; i < RANGE2; i += 256) {
        int node = n0 + i;
        if (node < N_NODES) v += deg[node];
    }
    s[tid] = v;
    __syncthreads();
    for (int off = 128; off > 0; off >>= 1) {
        if (tid < off) s[tid] += s[tid + off];
        __syncthreads();
    }
    if (tid == 0) rsum[q] = s[0];
}

// ---------------------------------------------------------------------------
// scanC_k: every block redundantly scans rsum[256] for its base, then scans
// its own 391 degrees (512-wide Hillis-Steele) -> row_ptr + cur.
// ---------------------------------------------------------------------------
__global__ __launch_bounds__(256) void scanC_k(const int* __restrict__ deg,
                                               const int* __restrict__ rsum,
                                               int* __restrict__ row_ptr,
                                               int* __restrict__ cur) {
    __shared__ int rs[256];
    __shared__ int hist[512];
    __shared__ int cnt[512];
    const int q = blockIdx.x;
    const int tid = threadIdx.x;

    rs[tid] = rsum[tid];
    __syncthreads();
    for (int off = 1; off < 256; off <<= 1) {
        int t = (tid >= off) ? rs[tid - off] : 0;
        __syncthreads();
        rs[tid] += t;
        __syncthreads();
    }
    const int base = (q > 0) ? rs[q - 1] : 0;
    const int n0 = q * RANGE2;

    {
        int i1 = tid + 256;
        int na = n0 + tid, nb = n0 + i1;
        int d0 = (tid < RANGE2 && na < N_NODES) ? deg[na] : 0;
        int d1 = (i1 < RANGE2 && nb < N_NODES) ? deg[nb] : 0;
        hist[tid] = d0; hist[tid + 256] = d1;
        cnt[tid] = d0;  cnt[tid + 256] = d1;
    }
    __syncthreads();
    for (int off = 1; off < 512; off <<= 1) {
        int v0 = (tid >= off) ? hist[tid - off] : 0;
        int v1 = hist[tid + 256 - off];
        __syncthreads();
        hist[tid] += v0;
        hist[tid + 256] += v1;
        __syncthreads();
    }
#pragma unroll
    for (int bb = 0; bb < 2; bb++) {
        int i = tid + 256 * bb;
        if (i < RANGE2) {
            int node = n0 + i;
            if (node < N_NODES) {
                int v = base + hist[i] - cnt[i];
                row_ptr[node] = v;
                cur[node] = v;
            }
        }
    }
    if (q == NR2 - 1 && tid == 0) row_ptr[N_NODES] = N_EDGES;
}

// ---------------------------------------------------------------------------
// scat_k: col[atomicAdd(&cur[dst])] = src.
// ---------------------------------------------------------------------------
__global__ __launch_bounds__(256) void scat_k(const int* __restrict__ src,
                                              const int* __restrict__ dst,
                                              int* __restrict__ cur,
                                              int* __restrict__ col) {
    const int b = blockIdx.x;
    const int tid = threadIdx.x;
#pragma unroll
    for (int it = 0; it < 4; it++) {
        int i = b * 1024 + it * 256 + tid;
        if (i < N_EDGES) {
            int d = dst[i];
            int pos = atomicAdd(&cur[d], 1);
            col[pos] = src[i];
        }
    }
}

// ---------------------------------------------------------------------------
// Aggregation: one HALF-WAVE (32 lanes) per node, bf16 rows, fp32 accumulate,
// bf16 output rows (RNE). Round-0 proven version.
// ---------------------------------------------------------------------------
__global__ __launch_bounds__(256) void agg_k(const unsigned short* __restrict__ h,
                                             const int* __restrict__ row_ptr,
                                             const int* __restrict__ col,
                                             unsigned short* __restrict__ z) {
    const int half = (blockIdx.x * blockDim.x + threadIdx.x) >> 5;  // node id
    const int lane = threadIdx.x & 31;
    const int halfbase = threadIdx.x & 32;
    if (half >= N_NODES) return;
    const us4* hp = (const us4*)h;  // 32 x us4 per row
    float4 acc = us4f(hp[(size_t)half * 32 + lane]);  // self term, (1+eps)=1
    const int beg = row_ptr[half];
    const int end = row_ptr[half + 1];

    for (int base = beg; base < end; base += 32) {
        const int n = min(32, end - base);
        int myidx = (lane < n) ? col[base + lane] : 0;
        int j = 0;
        for (; j + 4 <= n; j += 4) {
            int i0 = __shfl(myidx, halfbase + j + 0, 64);
            int i1 = __shfl(myidx, halfbase + j + 1, 64);
            int i2 = __shfl(myidx, halfbase + j + 2, 64);
            int i3 = __shfl(myidx, halfbase + j + 3, 64);
            float4 v0 = us4f(hp[(size_t)i0 * 32 + lane]);
            float4 v1 = us4f(hp[(size_t)i1 * 32 + lane]);
            float4 v2 = us4f(hp[(size_t)i2 * 32 + lane]);
            float4 v3 = us4f(hp[(size_t)i3 * 32 + lane]);
            acc.x += v0.x; acc.y += v0.y; acc.z += v0.z; acc.w += v0.w;
            acc.x += v1.x; acc.y += v1.y; acc.z += v1.z; acc.w += v1.w;
            acc.x += v2.x; acc.y += v2.y; acc.z += v2.z; acc.w += v2.w;
            acc.x += v3.x; acc.y += v3.y; acc.z += v3.z; acc.w += v3.w;
        }
        for (; j < n; j++) {
            int i0 = __shfl(myidx, halfbase + j, 64);
            float4 v0 = us4f(hp[(size_t)i0 * 32 + lane]);
            acc.x += v0.x; acc.y += v0.y; acc.z += v0.z; acc.w += v0.w;
        }
    }
    us4 o = {f2bf(acc.x), f2bf(acc.y), f2bf(acc.z), f2bf(acc.w)};
    ((us4*)z)[(size_t)half * 32 + lane] = o;   // bf16 row, 256B coalesced
}

// ---------------------------------------------------------------------------
// MFMA MLP (single-term bf16, fp32 accumulate):
//   h_out = ELU(ELU(z@Wa + ba)@Wb + bb); mlp3 fuses the final FC.
// ---------------------------------------------------------------------------
__device__ __forceinline__ void gemm1_g(
    const unsigned short* __restrict__ zrow,   // block-base z row pointer
    const unsigned short* __restrict__ Whi_g,
    const float* __restrict__ bias, int tid, f32x4 acc[2][4]) {
    const int L = tid & 63;
    const int w = tid >> 6;
    const int mt0 = (w >> 1) * 2;
    const int nt0 = (w & 1) * 4;
    const int lan15 = L & 15;
    const int quad = L >> 4;
#pragma unroll
    for (int n = 0; n < 4; n++) {
        float b = bias[(nt0 + n) * 16 + lan15];
        f32x4 bv = {b, b, b, b};
        acc[0][n] = bv;
        acc[1][n] = bv;
    }
    const unsigned short* rowA0 = zrow + (mt0 * 16 + lan15) * HID + quad * 8;
    const unsigned short* rowA1 = rowA0 + 16 * HID;
#pragma unroll
    for (int kb = 0; kb < 4; kb++) {
        short8 ah0 = *(const short8*)&rowA0[kb * 32];
        short8 ah1 = *(const short8*)&rowA1[kb * 32];
#pragma unroll
        for (int n = 0; n < 4; n++) {
            short8 bh = *(const short8*)&Whi_g[((kb * 8 + nt0 + n) * 64 + L) * 8];
            acc[0][n] = __builtin_amdgcn_mfma_f32_16x16x32_bf16(ah0, bh, acc[0][n], 0, 0, 0);
            acc[1][n] = __builtin_amdgcn_mfma_f32_16x16x32_bf16(ah1, bh, acc[1][n], 0, 0, 0);
        }
    }
}

__device__ __forceinline__ void gemm_lds(
    const unsigned short* Aph_,
    const unsigned short* __restrict__ Whi_g,
    const float* __restrict__ bias, int tid, f32x4 acc[2][4]) {
    const int L = tid & 63;
    const int w = tid >> 6;
    const int mt0 = (w >> 1) * 2;
    const int nt0 = (w & 1) * 4;
    const int lan15 = L & 15;
#pragma unroll
    for (int n = 0; n < 4; n++) {
        float b = bias[(nt0 + n) * 16 + lan15];
        f32x4 bv = {b, b, b, b};
        acc[0][n] = bv;
        acc[1][n] = bv;
    }
#pragma unroll
    for (int kb = 0; kb < 4; kb++) {
        short8 ah0 = *(const short8*)&Aph_[(((mt0 + 0) * 4 + kb) * 64 + L) * 8];
        short8 ah1 = *(const short8*)&Aph_[(((mt0 + 1) * 4 + kb) * 64 + L) * 8];
#pragma unroll
        for (int n = 0; n < 4; n++) {
            short8 bh = *(const short8*)&Whi_g[((kb * 8 + nt0 + n) * 64 + L) * 8];
            acc[0][n] = __builtin_amdgcn_mfma_f32_16x16x32_bf16(ah0, bh, acc[0][n], 0, 0, 0);
            acc[1][n] = __builtin_amdgcn_mfma_f32_16x16x32_bf16(ah1, bh, acc[1][n], 0, 0, 0);
        }
    }
}

template <int FC>
__device__ __forceinline__ void mlp_body(
    const unsigned short* __restrict__ zb,
    const unsigned short* __restrict__ Wahp,
    const unsigned short* __restrict__ Wbhp,
    const float* __restrict__ ba, const float* __restrict__ bb,
    unsigned short* __restrict__ hout,
    const unsigned short* __restrict__ fcWph,
    const float* __restrict__ fcb, float* __restrict__ out) {
    __shared__ unsigned short Aph[8192];   // 16 KB: packed t (bf16)

    const int tid = threadIdx.x;
    const int L = tid & 63;
    const int w = tid >> 6;
    const int mt0 = (w >> 1) * 2;
    const int nt0 = (w & 1) * 4;
    const int lan15 = L & 15;
    const int quad = L >> 4;
    const size_t node_base = (size_t)blockIdx.x * 64;

    // ---- GEMM1: t = ELU(z @ Wa + ba), A straight from global z rows ----
    {
        f32x4 acc[2][4];
        gemm1_g(zb + node_base * HID, Wahp, ba, tid, acc);
        // repack t (bf16) into A-frag LDS; writes are wave-disjoint
#pragma unroll
        for (int i = 0; i < 2; i++) {
#pragma unroll
            for (int n = 0; n < 4; n++) {
                int kdim = (nt0 + n) * 16 + lan15;
                int kb2 = kdim >> 5;
                int q2 = (kdim & 31) >> 3;
                int j2 = kdim & 7;
#pragma unroll
                for (int r = 0; r < 4; r++) {
                    float v = elu(acc[i][n][r]);
                    int mrow = quad * 4 + r;
                    int idx = (((mt0 + i) * 4 + kb2) * 64 + (mrow + 16 * q2)) * 8 + j2;
                    Aph[idx] = f2bf(v);
                }
            }
        }
    }
    __syncthreads();

    // ---- GEMM2: h = ELU(t @ Wb + bb) ----
    {
        f32x4 acc[2][4];
        gemm_lds(Aph, Wbhp, bb, tid, acc);
        if (FC == 0) {
#pragma unroll
            for (int i = 0; i < 2; i++) {
#pragma unroll
                for (int n = 0; n < 4; n++) {
                    int ncol = (nt0 + n) * 16 + lan15;
#pragma unroll
                    for (int r = 0; r < 4; r++) {
                        int mrow = (mt0 + i) * 16 + quad * 4 + r;
                        hout[(node_base + mrow) * HID + ncol] = f2bf(elu(acc[i][n][r]));
                    }
                }
            }
        } else {
            // repack h (bf16, identical rounding to stored-h path) for FC
            __syncthreads();
#pragma unroll
            for (int i = 0; i < 2; i++) {
#pragma unroll
                for (int n = 0; n < 4; n++) {
                    int kdim = (nt0 + n) * 16 + lan15;
                    int kb2 = kdim >> 5;
                    int q2 = (kdim & 31) >> 3;
                    int j2 = kdim & 7;
#pragma unroll
                    for (int r = 0; r < 4; r++) {
                        float v = elu(acc[i][n][r]);
                        int mrow = quad * 4 + r;
                        int idx = (((mt0 + i) * 4 + kb2) * 64 + (mrow + 16 * q2)) * 8 + j2;
                        Aph[idx] = f2bf(v);
                    }
                }
            }
            __syncthreads();
            // FC: waves 0 and 2 handle their 2 M-tiles vs N-tile 0
            if ((w & 1) == 0) {
#pragma unroll
                for (int i = 0; i < 2; i++) {
                    int mt = mt0 + i;
                    float b = (lan15 < N_CLASS) ? fcb[lan15] : 0.f;
                    f32x4 acc2 = {b, b, b, b};
#pragma unroll
                    for (int kb = 0; kb < 4; kb++) {
                        short8 a = *(const short8*)&Aph[((mt * 4 + kb) * 64 + L) * 8];
                        short8 bh = *(const short8*)&fcWph[(kb * 64 + L) * 8];
                        acc2 = __builtin_amdgcn_mfma_f32_16x16x32_bf16(a, bh, acc2, 0, 0, 0);
                    }
#pragma unroll
                    for (int r = 0; r < 4; r++) {
                        size_t node = node_base + mt * 16 + quad * 4 + r;
                        if (node < N_NODES && lan15 < N_CLASS)
                            out[node * N_CLASS + lan15] = acc2[r];
                    }
                }
            }
        }
    }
}

__global__ __launch_bounds__(256) void mlp2_k(
    const unsigned short* __restrict__ zb,
    const unsigned short* __restrict__ Wahp,
    const unsigned short* __restrict__ Wbhp,
    const float* __restrict__ ba, const float* __restrict__ bb,
    unsigned short* __restrict__ hout) {
    mlp_body<0>(zb, Wahp, Wbhp, ba, bb, hout, nullptr, nullptr, nullptr);
}

__global__ __launch_bounds__(256) void mlp3_k(
    const unsigned short* __restrict__ zb,
    const unsigned short* __restrict__ Wahp,
    const unsigned short* __restrict__ Wbhp,
    const float* __restrict__ ba, const float* __restrict__ bb,
    const unsigned short* __restrict__ fcWph,
    const float* __restrict__ fcb, float* __restrict__ out) {
    mlp_body<1>(zb, Wahp, Wbhp, ba, bb, nullptr, fcWph, fcb, out);
}

// ---------------------------------------------------------------------------

extern "C" void kernel_launch(void* const* d_in, const int* in_sizes, int n_in,
                              void* d_out, int out_size, void* d_ws, size_t ws_size,
                              hipStream_t stream) {
    const float* x = (const float*)d_in[0];
    const int* ei = (const int*)d_in[1];  // [2][E]
    // d_in[2] = edge_weight (unused by the reference forward)
    const float* Wa = (const float*)d_in[3];   // [3][128][128]
    const float* ba = (const float*)d_in[4];   // [3][128]
    const float* Wb = (const float*)d_in[5];
    const float* bb = (const float*)d_in[6];
    const float* fcW = (const float*)d_in[7];  // [128][10]
    const float* fcb = (const float*)d_in[8];  // [10]
    float* out = (float*)d_out;

    const int* src = ei;
    const int* dst = ei + N_EDGES;

    // workspace carve
    char* w = (char*)d_ws;
    unsigned short* zb = (unsigned short*)w; w += (size_t)N_PAD * HID * 2;  // bf16 z
    unsigned short* hb = (unsigned short*)w; w += (size_t)N_PAD * HID * 2;  // bf16 h
    int* row_ptr = (int*)w;  w += ((size_t)N_NODES + 8) * 4;
    int* deg = (int*)w;      w += (size_t)(NR2 * RANGE2) * 4;   // 100096
    int* cur = (int*)w;      w += (size_t)(NR2 * RANGE2) * 4;   // 100096
    int* rsum = (int*)w;     w += NR2 * 4;
    int* col = (int*)w;      w += (size_t)N_EDGES * 4;
    unsigned short* Whp = (unsigned short*)w; w += 6 * 16384 * 2;
    unsigned short* fcWph = (unsigned short*)w; w += 2048 * 2;

    // ---- CSR build: hist -> scan -> scatter ----
    hipMemsetAsync(deg, 0, (size_t)(NR2 * RANGE2) * 4, stream);
    const int SETUP_BLOCKS = EHIST_BLOCKS + CAST_BLOCKS + WSPLIT_BLOCKS + 1;
    setup_k<<<SETUP_BLOCKS, 256, 0, stream>>>(dst, deg, x, hb,
                                              Wa, Wb, Whp, fcW, fcWph);
    scanA_k<<<NR2, 256, 0, stream>>>(deg, rsum);
    scanC_k<<<NR2, 256, 0, stream>>>(deg, rsum, row_ptr, cur);
    scat_k<<<EHIST_BLOCKS, 256, 0, stream>>>(src, dst, cur, col);

    const int AGG_BLOCKS = (N_NODES * 32 + 255) / 256;  // one half-wave per node
    const int MLP_BLOCKS = (N_NODES + 63) / 64;         // 1563 (ws rows padded)

    // ---- layer 1 ----
    agg_k<<<AGG_BLOCKS, 256, 0, stream>>>(hb, row_ptr, col, zb);
    mlp2_k<<<MLP_BLOCKS, 256, 0, stream>>>(zb, Whp, Whp + 16384, ba, bb, hb);
    // ---- layer 2 ----
    agg_k<<<AGG_BLOCKS, 256, 0, stream>>>(hb, row_ptr, col, zb);
    mlp2_k<<<MLP_BLOCKS, 256, 0, stream>>>(zb, Whp + 2 * 16384, Whp + 3 * 16384,
                                           ba + 128, bb + 128, hb);
    // ---- layer 3: MLP + fused final FC ----
    agg_k<<<AGG_BLOCKS, 256, 0, stream>>>(hb, row_ptr, col, zb);
    mlp3_k<<<MLP_BLOCKS, 256, 0, stream>>>(zb, Whp + 4 * 16384, Whp + 5 * 16384,
                                           ba + 256, bb + 256,
                                           fcWph, fcb, out);
}

// Round 5
// 403.052 us; speedup vs baseline: 1.3809x; 1.3809x over previous
//
#include <hip/hip_runtime.h>
#include <hip/hip_bf16.h>
#include <math.h>

#define N_NODES 100000
#define N_PAD 100032   // padded row count for workspace feature buffers
#define N_EDGES 1600000
#define HID 128
#define N_CLASS 10

// edge partition params: 1024 dst-ranges of 98 nodes (1024*98 = 100352)
#define NRG 1024
#define RGSZ 98
#define PCAP 2048      // per-range packed capacity (expected ~1568, +12 sigma)
#define P_BLOCKS 512
#define P_SLICE (N_EDGES / P_BLOCKS)  // 3125
#define CAST_ITEMS (N_NODES * (HID / 4))   // 3.2M float4 units
#define CAST_BLOCKS ((CAST_ITEMS + 2047) / 2048)  // 1563
#define WSPLIT_BLOCKS 384                  // 6*16384/256

typedef float f32x4 __attribute__((ext_vector_type(4)));
typedef short short8 __attribute__((ext_vector_type(8)));
typedef unsigned short us4 __attribute__((ext_vector_type(4)));

// bf16 helpers (round-to-nearest-even)
__device__ __forceinline__ unsigned short f2bf(float x) {
    unsigned u = __float_as_uint(x);
    unsigned r = u + 0x7FFF + ((u >> 16) & 1);
    return (unsigned short)(r >> 16);
}
__device__ __forceinline__ float bf2f(unsigned short h) {
    return __uint_as_float(((unsigned)h) << 16);
}
__device__ __forceinline__ float elu(float x) {
    return x > 0.f ? x : (expf(x) - 1.f);
}
__device__ __forceinline__ float4 us4f(us4 v) {
    float4 o;
    o.x = bf2f(v.x); o.y = bf2f(v.y); o.z = bf2f(v.z); o.w = bf2f(v.w);
    return o;
}

// ---------------------------------------------------------------------------
// setup_k: fused edge-partition + x-cast + weight-pack (block-range dispatch).
//   blocks [0,512): 1024-way dst-range partition of edges (packed src|dloc<<17)
//   blocks [512,2075): fp32->bf16 cast of x
//   blocks [2075,2459): MLP weight pack to B-frag layout
//   block 2459: fcW pack + row_ptr[N]=E
// gcnt must be zeroed before this kernel (hipMemsetAsync).
// ---------------------------------------------------------------------------
__global__ __launch_bounds__(256) void setup_k(
    const int* __restrict__ src, const int* __restrict__ dst,
    int* __restrict__ gcnt, unsigned* __restrict__ gbuf,
    const float* __restrict__ x, unsigned short* __restrict__ hb,
    const float* __restrict__ Wa, const float* __restrict__ Wb,
    unsigned short* __restrict__ Whp,
    const float* __restrict__ fcW, unsigned short* __restrict__ fcWph,
    int* __restrict__ row_ptr) {
    __shared__ unsigned stash[P_SLICE];          // 12.5 KB
    __shared__ unsigned short rbuf[P_SLICE];     // 6.25 KB (range id < 1021)
    __shared__ int hist[NRG], cur[NRG], base[NRG];  // 12 KB
    const int b = blockIdx.x;
    const int tid = threadIdx.x;

    if (b < P_BLOCKS) {
        // ---- edge partition ----
        for (int i = tid; i < NRG; i += 256) { hist[i] = 0; cur[i] = 0; }
        __syncthreads();
        const int e0 = b * P_SLICE;
        for (int i = tid; i < P_SLICE; i += 256) {
            unsigned s = (unsigned)src[e0 + i];
            unsigned d = (unsigned)dst[e0 + i];
            unsigned r = d / RGSZ;             // magic-mul
            unsigned dloc = d - r * RGSZ;      // < 98 (7 bits)
            stash[i] = s | (dloc << 17);
            rbuf[i] = (unsigned short)r;
            atomicAdd(&hist[r], 1);
        }
        __syncthreads();
        for (int i = tid; i < NRG; i += 256)
            base[i] = atomicAdd(&gcnt[i], hist[i]);
        __syncthreads();
        for (int i = tid; i < P_SLICE; i += 256) {
            unsigned r = rbuf[i];
            int off = atomicAdd(&cur[r], 1);
            int pos = base[r] + off;
            if (pos < PCAP) gbuf[(size_t)r * PCAP + pos] = stash[i];
        }
    } else if (b < P_BLOCKS + CAST_BLOCKS) {
        // ---- x cast ----
        const int cb = b - P_BLOCKS;
#pragma unroll
        for (int it = 0; it < 8; it++) {
            int i = cb * 2048 + it * 256 + tid;
            if (i < CAST_ITEMS) {
                float4 v = ((const float4*)x)[i];
                us4 o = {f2bf(v.x), f2bf(v.y), f2bf(v.z), f2bf(v.w)};
                ((us4*)hb)[i] = o;
            }
        }
    } else if (b < P_BLOCKS + CAST_BLOCKS + WSPLIT_BLOCKS) {
        // ---- MLP weight pack ----
        int f = (b - P_BLOCKS - CAST_BLOCKS) * 256 + tid;  // < 98304
        int g = f >> 14;
        int r = f & 16383;
        int j = r & 7;
        int L = (r >> 3) & 63;
        int t = r >> 9;
        int kb = t >> 3, nt = t & 7;
        int k = kb * 32 + ((L >> 4) & 3) * 8 + j;
        int n = nt * 16 + (L & 15);
        int layer = g >> 1;
        const float* W = (g & 1) ? Wb : Wa;
        Whp[f] = f2bf(W[layer * 16384 + k * 128 + n]);
    } else {
        // ---- fcW pack + row_ptr tail ----
#pragma unroll
        for (int it = 0; it < 8; it++) {
            int f = it * 256 + tid;  // < 2048
            int j = f & 7;
            int L = (f >> 3) & 63;
            int kb = f >> 9;
            int k = kb * 32 + ((L >> 4) & 3) * 8 + j;
            int n = L & 15;
            fcWph[f] = f2bf((n < N_CLASS) ? fcW[k * N_CLASS + n] : 0.f);
        }
        if (tid == 0) row_ptr[N_NODES] = N_EDGES;
    }
}

// ---------------------------------------------------------------------------
// csort_k: per-range LDS counting sort, 1024 blocks (4/CU for TLP).
// Each block: in-LDS exclusive scan of gcnt[1024] (4 elems/thread) for its
// col base, 98-bin histogram + 128-wide scan, LDS scatter, sequential col
// write (full lines). row_ptr written here.
// ---------------------------------------------------------------------------
__global__ __launch_bounds__(256) void csort_k(const unsigned* __restrict__ gbuf,
                                               const int* __restrict__ gcnt,
                                               int* __restrict__ row_ptr,
                                               int* __restrict__ col) {
    __shared__ int sorted[PCAP];    // 8 KB
    __shared__ int arr[NRG];        // 4 KB: exclusive prefix of gcnt
    __shared__ int tot[256];
    __shared__ int hist[128], cnt[128], run[128];
    const int q = blockIdx.x;
    const int tid = threadIdx.x;

    // ---- exclusive scan of gcnt[1024], 4 elements per thread ----
    {
        int4 g = ((const int4*)gcnt)[tid];
        int s0 = g.x;
        int s01 = s0 + g.y;
        int s012 = s01 + g.z;
        int s0123 = s012 + g.w;
        tot[tid] = s0123;
        __syncthreads();
        for (int off = 1; off < 256; off <<= 1) {
            int t = (tid >= off) ? tot[tid - off] : 0;
            __syncthreads();
            tot[tid] += t;
            __syncthreads();
        }
        int eb = tot[tid] - s0123;   // exclusive base for this thread's 4
        arr[4 * tid + 0] = eb;
        arr[4 * tid + 1] = eb + s0;
        arr[4 * tid + 2] = eb + s01;
        arr[4 * tid + 3] = eb + s012;
    }
    __syncthreads();
    const int cb = arr[q];
    const int n2 = min(gcnt[q], PCAP);
    const int node0 = q * RGSZ;
    const unsigned* buf = gbuf + (size_t)q * PCAP;

    if (tid < 128) hist[tid] = 0;
    __syncthreads();
    for (int i = tid; i < n2; i += 256)
        atomicAdd(&hist[buf[i] >> 17], 1);
    __syncthreads();
    if (tid < 128) cnt[tid] = hist[tid];
    __syncthreads();
    for (int off = 1; off < 128; off <<= 1) {
        int t = 0;
        if (tid < 128 && tid >= off) t = hist[tid - off];
        __syncthreads();
        if (tid < 128) hist[tid] += t;
        __syncthreads();
    }
    if (tid < RGSZ) {
        int excl = hist[tid] - cnt[tid];
        run[tid] = excl;
        int node = node0 + tid;
        if (node < N_NODES) row_ptr[node] = cb + excl;
    }
    __syncthreads();
    for (int i = tid; i < n2; i += 256) {
        unsigned wv = buf[i];
        int pos = atomicAdd(&run[wv >> 17], 1);
        sorted[pos] = (int)(wv & 0x1FFFF);
    }
    __syncthreads();
    for (int i = tid; i < n2; i += 256) col[cb + i] = sorted[i];
}

// ---------------------------------------------------------------------------
// Aggregation: one HALF-WAVE (32 lanes) per node, bf16 rows, fp32 accumulate,
// bf16 output rows (RNE). Round-0 proven version, untouched.
// ---------------------------------------------------------------------------
__global__ __launch_bounds__(256) void agg_k(const unsigned short* __restrict__ h,
                                             const int* __restrict__ row_ptr,
                                             const int* __restrict__ col,
                                             unsigned short* __restrict__ z) {
    const int half = (blockIdx.x * blockDim.x + threadIdx.x) >> 5;  // node id
    const int lane = threadIdx.x & 31;
    const int halfbase = threadIdx.x & 32;
    if (half >= N_NODES) return;
    const us4* hp = (const us4*)h;  // 32 x us4 per row
    float4 acc = us4f(hp[(size_t)half * 32 + lane]);  // self term, (1+eps)=1
    const int beg = row_ptr[half];
    const int end = row_ptr[half + 1];

    for (int base = beg; base < end; base += 32) {
        const int n = min(32, end - base);
        int myidx = (lane < n) ? col[base + lane] : 0;
        int j = 0;
        for (; j + 4 <= n; j += 4) {
            int i0 = __shfl(myidx, halfbase + j + 0, 64);
            int i1 = __shfl(myidx, halfbase + j + 1, 64);
            int i2 = __shfl(myidx, halfbase + j + 2, 64);
            int i3 = __shfl(myidx, halfbase + j + 3, 64);
            float4 v0 = us4f(hp[(size_t)i0 * 32 + lane]);
            float4 v1 = us4f(hp[(size_t)i1 * 32 + lane]);
            float4 v2 = us4f(hp[(size_t)i2 * 32 + lane]);
            float4 v3 = us4f(hp[(size_t)i3 * 32 + lane]);
            acc.x += v0.x; acc.y += v0.y; acc.z += v0.z; acc.w += v0.w;
            acc.x += v1.x; acc.y += v1.y; acc.z += v1.z; acc.w += v1.w;
            acc.x += v2.x; acc.y += v2.y; acc.z += v2.z; acc.w += v2.w;
            acc.x += v3.x; acc.y += v3.y; acc.z += v3.z; acc.w += v3.w;
        }
        for (; j < n; j++) {
            int i0 = __shfl(myidx, halfbase + j, 64);
            float4 v0 = us4f(hp[(size_t)i0 * 32 + lane]);
            acc.x += v0.x; acc.y += v0.y; acc.z += v0.z; acc.w += v0.w;
        }
    }
    us4 o = {f2bf(acc.x), f2bf(acc.y), f2bf(acc.z), f2bf(acc.w)};
    ((us4*)z)[(size_t)half * 32 + lane] = o;   // bf16 row, 256B coalesced
}

// ---------------------------------------------------------------------------
// MFMA MLP (single-term bf16, fp32 accumulate):
//   h_out = ELU(ELU(z@Wa + ba)@Wb + bb); mlp3 fuses the final FC.
// ---------------------------------------------------------------------------
__device__ __forceinline__ void gemm1_g(
    const unsigned short* __restrict__ zrow,   // block-base z row pointer
    const unsigned short* __restrict__ Whi_g,
    const float* __restrict__ bias, int tid, f32x4 acc[2][4]) {
    const int L = tid & 63;
    const int w = tid >> 6;
    const int mt0 = (w >> 1) * 2;
    const int nt0 = (w & 1) * 4;
    const int lan15 = L & 15;
    const int quad = L >> 4;
#pragma unroll
    for (int n = 0; n < 4; n++) {
        float b = bias[(nt0 + n) * 16 + lan15];
        f32x4 bv = {b, b, b, b};
        acc[0][n] = bv;
        acc[1][n] = bv;
    }
    const unsigned short* rowA0 = zrow + (mt0 * 16 + lan15) * HID + quad * 8;
    const unsigned short* rowA1 = rowA0 + 16 * HID;
#pragma unroll
    for (int kb = 0; kb < 4; kb++) {
        short8 ah0 = *(const short8*)&rowA0[kb * 32];
        short8 ah1 = *(const short8*)&rowA1[kb * 32];
#pragma unroll
        for (int n = 0; n < 4; n++) {
            short8 bh = *(const short8*)&Whi_g[((kb * 8 + nt0 + n) * 64 + L) * 8];
            acc[0][n] = __builtin_amdgcn_mfma_f32_16x16x32_bf16(ah0, bh, acc[0][n], 0, 0, 0);
            acc[1][n] = __builtin_amdgcn_mfma_f32_16x16x32_bf16(ah1, bh, acc[1][n], 0, 0, 0);
        }
    }
}

__device__ __forceinline__ void gemm_lds(
    const unsigned short* Aph_,
    const unsigned short* __restrict__ Whi_g,
    const float* __restrict__ bias, int tid, f32x4 acc[2][4]) {
    const int L = tid & 63;
    const int w = tid >> 6;
    const int mt0 = (w >> 1) * 2;
    const int nt0 = (w & 1) * 4;
    const int lan15 = L & 15;
#pragma unroll
    for (int n = 0; n < 4; n++) {
        float b = bias[(nt0 + n) * 16 + lan15];
        f32x4 bv = {b, b, b, b};
        acc[0][n] = bv;
        acc[1][n] = bv;
    }
#pragma unroll
    for (int kb = 0; kb < 4; kb++) {
        short8 ah0 = *(const short8*)&Aph_[(((mt0 + 0) * 4 + kb) * 64 + L) * 8];
        short8 ah1 = *(const short8*)&Aph_[(((mt0 + 1) * 4 + kb) * 64 + L) * 8];
#pragma unroll
        for (int n = 0; n < 4; n++) {
            short8 bh = *(const short8*)&Whi_g[((kb * 8 + nt0 + n) * 64 + L) * 8];
            acc[0][n] = __builtin_amdgcn_mfma_f32_16x16x32_bf16(ah0, bh, acc[0][n], 0, 0, 0);
            acc[1][n] = __builtin_amdgcn_mfma_f32_16x16x32_bf16(ah1, bh, acc[1][n], 0, 0, 0);
        }
    }
}

template <int FC>
__device__ __forceinline__ void mlp_body(
    const unsigned short* __restrict__ zb,
    const unsigned short* __restrict__ Wahp,
    const unsigned short* __restrict__ Wbhp,
    const float* __restrict__ ba, const float* __restrict__ bb,
    unsigned short* __restrict__ hout,
    const unsigned short* __restrict__ fcWph,
    const float* __restrict__ fcb, float* __restrict__ out) {
    __shared__ unsigned short Aph[8192];   // 16 KB: packed t (bf16)

    const int tid = threadIdx.x;
    const int L = tid & 63;
    const int w = tid >> 6;
    const int mt0 = (w >> 1) * 2;
    const int nt0 = (w & 1) * 4;
    const int lan15 = L & 15;
    const int quad = L >> 4;
    const size_t node_base = (size_t)blockIdx.x * 64;

    // ---- GEMM1: t = ELU(z @ Wa + ba), A straight from global z rows ----
    {
        f32x4 acc[2][4];
        gemm1_g(zb + node_base * HID, Wahp, ba, tid, acc);
        // repack t (bf16) into A-frag LDS; writes are wave-disjoint
#pragma unroll
        for (int i = 0; i < 2; i++) {
#pragma unroll
            for (int n = 0; n < 4; n++) {
                int kdim = (nt0 + n) * 16 + lan15;
                int kb2 = kdim >> 5;
                int q2 = (kdim & 31) >> 3;
                int j2 = kdim & 7;
#pragma unroll
                for (int r = 0; r < 4; r++) {
                    float v = elu(acc[i][n][r]);
                    int mrow = quad * 4 + r;
                    int idx = (((mt0 + i) * 4 + kb2) * 64 + (mrow + 16 * q2)) * 8 + j2;
                    Aph[idx] = f2bf(v);
                }
            }
        }
    }
    __syncthreads();

    // ---- GEMM2: h = ELU(t @ Wb + bb) ----
    {
        f32x4 acc[2][4];
        gemm_lds(Aph, Wbhp, bb, tid, acc);
        if (FC == 0) {
#pragma unroll
            for (int i = 0; i < 2; i++) {
#pragma unroll
                for (int n = 0; n < 4; n++) {
                    int ncol = (nt0 + n) * 16 + lan15;
#pragma unroll
                    for (int r = 0; r < 4; r++) {
                        int mrow = (mt0 + i) * 16 + quad * 4 + r;
                        hout[(node_base + mrow) * HID + ncol] = f2bf(elu(acc[i][n][r]));
                    }
                }
            }
        } else {
            // repack h (bf16, identical rounding to stored-h path) for FC
            __syncthreads();
#pragma unroll
            for (int i = 0; i < 2; i++) {
#pragma unroll
                for (int n = 0; n < 4; n++) {
                    int kdim = (nt0 + n) * 16 + lan15;
                    int kb2 = kdim >> 5;
                    int q2 = (kdim & 31) >> 3;
                    int j2 = kdim & 7;
#pragma unroll
                    for (int r = 0; r < 4; r++) {
                        float v = elu(acc[i][n][r]);
                        int mrow = quad * 4 + r;
                        int idx = (((mt0 + i) * 4 + kb2) * 64 + (mrow + 16 * q2)) * 8 + j2;
                        Aph[idx] = f2bf(v);
                    }
                }
            }
            __syncthreads();
            // FC: waves 0 and 2 handle their 2 M-tiles vs N-tile 0
            if ((w & 1) == 0) {
#pragma unroll
                for (int i = 0; i < 2; i++) {
                    int mt = mt0 + i;
                    float b = (lan15 < N_CLASS) ? fcb[lan15] : 0.f;
                    f32x4 acc2 = {b, b, b, b};
#pragma unroll
                    for (int kb = 0; kb < 4; kb++) {
                        short8 a = *(const short8*)&Aph[((mt * 4 + kb) * 64 + L) * 8];
                        short8 bh = *(const short8*)&fcWph[(kb * 64 + L) * 8];
                        acc2 = __builtin_amdgcn_mfma_f32_16x16x32_bf16(a, bh, acc2, 0, 0, 0);
                    }
#pragma unroll
                    for (int r = 0; r < 4; r++) {
                        size_t node = node_base + mt * 16 + quad * 4 + r;
                        if (node < N_NODES && lan15 < N_CLASS)
                            out[node * N_CLASS + lan15] = acc2[r];
                    }
                }
            }
        }
    }
}

__global__ __launch_bounds__(256) void mlp2_k(
    const unsigned short* __restrict__ zb,
    const unsigned short* __restrict__ Wahp,
    const unsigned short* __restrict__ Wbhp,
    const float* __restrict__ ba, const float* __restrict__ bb,
    unsigned short* __restrict__ hout) {
    mlp_body<0>(zb, Wahp, Wbhp, ba, bb, hout, nullptr, nullptr, nullptr);
}

__global__ __launch_bounds__(256) void mlp3_k(
    const unsigned short* __restrict__ zb,
    const unsigned short* __restrict__ Wahp,
    const unsigned short* __restrict__ Wbhp,
    const float* __restrict__ ba, const float* __restrict__ bb,
    const unsigned short* __restrict__ fcWph,
    const float* __restrict__ fcb, float* __restrict__ out) {
    mlp_body<1>(zb, Wahp, Wbhp, ba, bb, nullptr, fcWph, fcb, out);
}

// ---------------------------------------------------------------------------

extern "C" void kernel_launch(void* const* d_in, const int* in_sizes, int n_in,
                              void* d_out, int out_size, void* d_ws, size_t ws_size,
                              hipStream_t stream) {
    const float* x = (const float*)d_in[0];
    const int* ei = (const int*)d_in[1];  // [2][E]
    // d_in[2] = edge_weight (unused by the reference forward)
    const float* Wa = (const float*)d_in[3];   // [3][128][128]
    const float* ba = (const float*)d_in[4];   // [3][128]
    const float* Wb = (const float*)d_in[5];
    const float* bb = (const float*)d_in[6];
    const float* fcW = (const float*)d_in[7];  // [128][10]
    const float* fcb = (const float*)d_in[8];  // [10]
    float* out = (float*)d_out;

    const int* src = ei;
    const int* dst = ei + N_EDGES;

    // workspace carve
    char* w = (char*)d_ws;
    unsigned short* zb = (unsigned short*)w; w += (size_t)N_PAD * HID * 2;  // bf16 z
    unsigned short* hb = (unsigned short*)w; w += (size_t)N_PAD * HID * 2;  // bf16 h
    int* row_ptr = (int*)w;  w += ((size_t)N_NODES + 8) * 4;
    int* gcnt = (int*)w;     w += NRG * 4;
    int* col = (int*)w;      w += (size_t)N_EDGES * 4;
    unsigned short* Whp = (unsigned short*)w; w += 6 * 16384 * 2;
    unsigned short* fcWph = (unsigned short*)w; w += 2048 * 2;
    unsigned* gbuf = (unsigned*)w; w += (size_t)NRG * PCAP * 4;  // 8 MB

    // ---- setup: partition + cast + weight pack (one fused kernel) ----
    hipMemsetAsync(gcnt, 0, NRG * 4, stream);
    const int SETUP_BLOCKS = P_BLOCKS + CAST_BLOCKS + WSPLIT_BLOCKS + 1;
    setup_k<<<SETUP_BLOCKS, 256, 0, stream>>>(src, dst, gcnt, gbuf, x, hb,
                                              Wa, Wb, Whp, fcW, fcWph, row_ptr);
    // ---- counting sort -> CSR ----
    csort_k<<<NRG, 256, 0, stream>>>(gbuf, gcnt, row_ptr, col);

    const int AGG_BLOCKS = (N_NODES * 32 + 255) / 256;  // one half-wave per node
    const int MLP_BLOCKS = (N_NODES + 63) / 64;         // 1563 (ws rows padded)

    // ---- layer 1 ----
    agg_k<<<AGG_BLOCKS, 256, 0, stream>>>(hb, row_ptr, col, zb);
    mlp2_k<<<MLP_BLOCKS, 256, 0, stream>>>(zb, Whp, Whp + 16384, ba, bb, hb);
    // ---- layer 2 ----
    agg_k<<<AGG_BLOCKS, 256, 0, stream>>>(hb, row_ptr, col, zb);
    mlp2_k<<<MLP_BLOCKS, 256, 0, stream>>>(zb, Whp + 2 * 16384, Whp + 3 * 16384,
                                           ba + 128, bb + 128, hb);
    // ---- layer 3: MLP + fused final FC ----
    agg_k<<<AGG_BLOCKS, 256, 0, stream>>>(hb, row_ptr, col, zb);
    mlp3_k<<<MLP_BLOCKS, 256, 0, stream>>>(zb, Whp + 4 * 16384, Whp + 5 * 16384,
                                           ba + 256, bb + 256,
                                           fcWph, fcb, out);
}

// Round 6
// 393.901 us; speedup vs baseline: 1.4130x; 1.0232x over previous
//
#include <hip/hip_runtime.h>
#include <hip/hip_bf16.h>
#include <math.h>

#define N_NODES 100000
#define N_PAD 100032   // padded row count for workspace feature buffers
#define N_EDGES 1600000
#define HID 128
#define N_CLASS 10

// edge partition params: 1024 dst-ranges of 98 nodes (1024*98 = 100352)
#define NRG 1024
#define RGSZ 98
#define PCAP 2048      // per-range packed capacity (expected ~1568, +12 sigma)
#define GSTRIDE 16     // gcnt padding: one counter per 64B line (atomic contention fix)
#define P_BLOCKS 512
#define P_SLICE (N_EDGES / P_BLOCKS)  // 3125
#define CAST_ITEMS (N_NODES * (HID / 4))   // 3.2M float4 units
#define CAST_BLOCKS ((CAST_ITEMS + 2047) / 2048)  // 1563
#define WSPLIT_BLOCKS 384                  // 6*16384/256

#define NXCD 8
#define AGG_GRID 12500   // 8 nodes per block
#define MLP_GRID 1563    // 64 nodes per block

typedef float f32x4 __attribute__((ext_vector_type(4)));
typedef short short8 __attribute__((ext_vector_type(8)));
typedef unsigned short us4 __attribute__((ext_vector_type(4)));

// bf16 helpers (round-to-nearest-even)
__device__ __forceinline__ unsigned short f2bf(float x) {
    unsigned u = __float_as_uint(x);
    unsigned r = u + 0x7FFF + ((u >> 16) & 1);
    return (unsigned short)(r >> 16);
}
__device__ __forceinline__ float bf2f(unsigned short h) {
    return __uint_as_float(((unsigned)h) << 16);
}
__device__ __forceinline__ float elu(float x) {
    return x > 0.f ? x : (__expf(x) - 1.f);
}
__device__ __forceinline__ float4 us4f(us4 v) {
    float4 o;
    o.x = bf2f(v.x); o.y = bf2f(v.y); o.z = bf2f(v.z); o.w = bf2f(v.w);
    return o;
}

// bijective XCD-affinity remap: block bid (grid = n) -> work chunk, such that
// XCD x (= bid % 8 under round-robin dispatch) owns a contiguous chunk range.
// q = n/8, r = n%8; xcd x gets cnt = q + (x<r) chunks starting at x*q + min(x,r).
__device__ __forceinline__ int xcd_swz(int bid, int q, int r) {
    int x = bid & (NXCD - 1);
    int k = bid >> 3;
    return x * q + (x < r ? x : r) + k;
}

// ---------------------------------------------------------------------------
// setup_k: fused edge-partition + x-cast + weight-pack (block-range dispatch).
//   blocks [0,512): 1024-way dst-range partition of edges (packed src|dloc<<17)
//   blocks [512,2075): fp32->bf16 cast of x
//   blocks [2075,2459): MLP weight pack to B-frag layout
//   block 2459: fcW pack + row_ptr[N]=E
// gcnt (padded, stride GSTRIDE) must be zeroed before this kernel.
// ---------------------------------------------------------------------------
__global__ __launch_bounds__(256) void setup_k(
    const int* __restrict__ src, const int* __restrict__ dst,
    int* __restrict__ gcnt, unsigned* __restrict__ gbuf,
    const float* __restrict__ x, unsigned short* __restrict__ hb,
    const float* __restrict__ Wa, const float* __restrict__ Wb,
    unsigned short* __restrict__ Whp,
    const float* __restrict__ fcW, unsigned short* __restrict__ fcWph,
    int* __restrict__ row_ptr) {
    __shared__ unsigned stash[P_SLICE];          // 12.5 KB
    __shared__ unsigned short rbuf[P_SLICE];     // 6.25 KB (range id < 1021)
    __shared__ int hist[NRG], cur[NRG], base[NRG];  // 12 KB
    const int b = blockIdx.x;
    const int tid = threadIdx.x;

    if (b < P_BLOCKS) {
        // ---- edge partition ----
        for (int i = tid; i < NRG; i += 256) { hist[i] = 0; cur[i] = 0; }
        __syncthreads();
        const int e0 = b * P_SLICE;
        for (int i = tid; i < P_SLICE; i += 256) {
            unsigned s = (unsigned)src[e0 + i];
            unsigned d = (unsigned)dst[e0 + i];
            unsigned r = d / RGSZ;             // magic-mul
            unsigned dloc = d - r * RGSZ;      // < 98 (7 bits)
            stash[i] = s | (dloc << 17);
            rbuf[i] = (unsigned short)r;
            atomicAdd(&hist[r], 1);
        }
        __syncthreads();
        for (int i = tid; i < NRG; i += 256)
            base[i] = atomicAdd(&gcnt[i * GSTRIDE], hist[i]);  // 1 counter/line
        __syncthreads();
        for (int i = tid; i < P_SLICE; i += 256) {
            unsigned r = rbuf[i];
            int off = atomicAdd(&cur[r], 1);
            int pos = base[r] + off;
            if (pos < PCAP) gbuf[(size_t)r * PCAP + pos] = stash[i];
        }
    } else if (b < P_BLOCKS + CAST_BLOCKS) {
        // ---- x cast ----
        const int cb = b - P_BLOCKS;
#pragma unroll
        for (int it = 0; it < 8; it++) {
            int i = cb * 2048 + it * 256 + tid;
            if (i < CAST_ITEMS) {
                float4 v = ((const float4*)x)[i];
                us4 o = {f2bf(v.x), f2bf(v.y), f2bf(v.z), f2bf(v.w)};
                ((us4*)hb)[i] = o;
            }
        }
    } else if (b < P_BLOCKS + CAST_BLOCKS + WSPLIT_BLOCKS) {
        // ---- MLP weight pack ----
        int f = (b - P_BLOCKS - CAST_BLOCKS) * 256 + tid;  // < 98304
        int g = f >> 14;
        int r = f & 16383;
        int j = r & 7;
        int L = (r >> 3) & 63;
        int t = r >> 9;
        int kb = t >> 3, nt = t & 7;
        int k = kb * 32 + ((L >> 4) & 3) * 8 + j;
        int n = nt * 16 + (L & 15);
        int layer = g >> 1;
        const float* W = (g & 1) ? Wb : Wa;
        Whp[f] = f2bf(W[layer * 16384 + k * 128 + n]);
    } else {
        // ---- fcW pack + row_ptr tail ----
#pragma unroll
        for (int it = 0; it < 8; it++) {
            int f = it * 256 + tid;  // < 2048
            int j = f & 7;
            int L = (f >> 3) & 63;
            int kb = f >> 9;
            int k = kb * 32 + ((L >> 4) & 3) * 8 + j;
            int n = L & 15;
            fcWph[f] = f2bf((n < N_CLASS) ? fcW[k * N_CLASS + n] : 0.f);
        }
        if (tid == 0) row_ptr[N_NODES] = N_EDGES;
    }
}

// ---------------------------------------------------------------------------
// csort_k: per-range LDS counting sort, 1024 blocks.
// ---------------------------------------------------------------------------
__global__ __launch_bounds__(256) void csort_k(const unsigned* __restrict__ gbuf,
                                               const int* __restrict__ gcnt,
                                               int* __restrict__ row_ptr,
                                               int* __restrict__ col) {
    __shared__ int sorted[PCAP];    // 8 KB
    __shared__ int arr[NRG];        // 4 KB: exclusive prefix of gcnt
    __shared__ int tot[256];
    __shared__ int hist[128], cnt[128], run[128];
    const int q = blockIdx.x;
    const int tid = threadIdx.x;

    // ---- exclusive scan of gcnt[1024] (stride GSTRIDE), 4 per thread ----
    {
        int g0 = gcnt[(4 * tid + 0) * GSTRIDE];
        int g1 = gcnt[(4 * tid + 1) * GSTRIDE];
        int g2 = gcnt[(4 * tid + 2) * GSTRIDE];
        int g3 = gcnt[(4 * tid + 3) * GSTRIDE];
        int s0 = g0;
        int s01 = s0 + g1;
        int s012 = s01 + g2;
        int s0123 = s012 + g3;
        tot[tid] = s0123;
        __syncthreads();
        for (int off = 1; off < 256; off <<= 1) {
            int t = (tid >= off) ? tot[tid - off] : 0;
            __syncthreads();
            tot[tid] += t;
            __syncthreads();
        }
        int eb = tot[tid] - s0123;   // exclusive base for this thread's 4
        arr[4 * tid + 0] = eb;
        arr[4 * tid + 1] = eb + s0;
        arr[4 * tid + 2] = eb + s01;
        arr[4 * tid + 3] = eb + s012;
    }
    __syncthreads();
    const int cb = arr[q];
    const int n2 = min(gcnt[q * GSTRIDE], PCAP);
    const int node0 = q * RGSZ;
    const unsigned* buf = gbuf + (size_t)q * PCAP;

    if (tid < 128) hist[tid] = 0;
    __syncthreads();
    for (int i = tid; i < n2; i += 256)
        atomicAdd(&hist[buf[i] >> 17], 1);
    __syncthreads();
    if (tid < 128) cnt[tid] = hist[tid];
    __syncthreads();
    for (int off = 1; off < 128; off <<= 1) {
        int t = 0;
        if (tid < 128 && tid >= off) t = hist[tid - off];
        __syncthreads();
        if (tid < 128) hist[tid] += t;
        __syncthreads();
    }
    if (tid < RGSZ) {
        int excl = hist[tid] - cnt[tid];
        run[tid] = excl;
        int node = node0 + tid;
        if (node < N_NODES) row_ptr[node] = cb + excl;
    }
    __syncthreads();
    for (int i = tid; i < n2; i += 256) {
        unsigned wv = buf[i];
        int pos = atomicAdd(&run[wv >> 17], 1);
        sorted[pos] = (int)(wv & 0x1FFFF);
    }
    __syncthreads();
    for (int i = tid; i < n2; i += 256) col[cb + i] = sorted[i];
}

// ---------------------------------------------------------------------------
// Aggregation: one HALF-WAVE (32 lanes) per node, bf16 rows, fp32 accumulate,
// bf16 output rows (RNE). XCD-affinity block swizzle: XCD x owns a contiguous
// node range, matching mlp's swizzle, so self-term h reads and z writes stay
// in-XCD. Per-node accumulation order unchanged -> bit-identical output.
// ---------------------------------------------------------------------------
__global__ __launch_bounds__(256) void agg_k(const unsigned short* __restrict__ h,
                                             const int* __restrict__ row_ptr,
                                             const int* __restrict__ col,
                                             unsigned short* __restrict__ z) {
    // AGG_GRID = 12500: q = 1562, r = 4
    const int blk = xcd_swz(blockIdx.x, AGG_GRID / NXCD, AGG_GRID % NXCD);
    const int half = blk * 8 + (threadIdx.x >> 5);  // node id
    const int lane = threadIdx.x & 31;
    const int halfbase = threadIdx.x & 32;
    if (half >= N_NODES) return;
    const us4* hp = (const us4*)h;  // 32 x us4 per row
    float4 acc = us4f(hp[(size_t)half * 32 + lane]);  // self term, (1+eps)=1
    const int beg = row_ptr[half];
    const int end = row_ptr[half + 1];

    for (int base = beg; base < end; base += 32) {
        const int n = min(32, end - base);
        int myidx = (lane < n) ? col[base + lane] : 0;
        int j = 0;
        for (; j + 4 <= n; j += 4) {
            int i0 = __shfl(myidx, halfbase + j + 0, 64);
            int i1 = __shfl(myidx, halfbase + j + 1, 64);
            int i2 = __shfl(myidx, halfbase + j + 2, 64);
            int i3 = __shfl(myidx, halfbase + j + 3, 64);
            float4 v0 = us4f(hp[(size_t)i0 * 32 + lane]);
            float4 v1 = us4f(hp[(size_t)i1 * 32 + lane]);
            float4 v2 = us4f(hp[(size_t)i2 * 32 + lane]);
            float4 v3 = us4f(hp[(size_t)i3 * 32 + lane]);
            acc.x += v0.x; acc.y += v0.y; acc.z += v0.z; acc.w += v0.w;
            acc.x += v1.x; acc.y += v1.y; acc.z += v1.z; acc.w += v1.w;
            acc.x += v2.x; acc.y += v2.y; acc.z += v2.z; acc.w += v2.w;
            acc.x += v3.x; acc.y += v3.y; acc.z += v3.z; acc.w += v3.w;
        }
        for (; j < n; j++) {
            int i0 = __shfl(myidx, halfbase + j, 64);
            float4 v0 = us4f(hp[(size_t)i0 * 32 + lane]);
            acc.x += v0.x; acc.y += v0.y; acc.z += v0.z; acc.w += v0.w;
        }
    }
    us4 o = {f2bf(acc.x), f2bf(acc.y), f2bf(acc.z), f2bf(acc.w)};
    ((us4*)z)[(size_t)half * 32 + lane] = o;   // bf16 row, 256B coalesced
}

// ---------------------------------------------------------------------------
// MFMA MLP (single-term bf16, fp32 accumulate):
//   h_out = ELU(ELU(z@Wa + ba)@Wb + bb); mlp3 fuses the final FC.
// ---------------------------------------------------------------------------
__device__ __forceinline__ void gemm1_g(
    const unsigned short* __restrict__ zrow,   // block-base z row pointer
    const unsigned short* __restrict__ Whi_g,
    const float* __restrict__ bias, int tid, f32x4 acc[2][4]) {
    const int L = tid & 63;
    const int w = tid >> 6;
    const int mt0 = (w >> 1) * 2;
    const int nt0 = (w & 1) * 4;
    const int lan15 = L & 15;
    const int quad = L >> 4;
#pragma unroll
    for (int n = 0; n < 4; n++) {
        float b = bias[(nt0 + n) * 16 + lan15];
        f32x4 bv = {b, b, b, b};
        acc[0][n] = bv;
        acc[1][n] = bv;
    }
    const unsigned short* rowA0 = zrow + (mt0 * 16 + lan15) * HID + quad * 8;
    const unsigned short* rowA1 = rowA0 + 16 * HID;
#pragma unroll
    for (int kb = 0; kb < 4; kb++) {
        short8 ah0 = *(const short8*)&rowA0[kb * 32];
        short8 ah1 = *(const short8*)&rowA1[kb * 32];
#pragma unroll
        for (int n = 0; n < 4; n++) {
            short8 bh = *(const short8*)&Whi_g[((kb * 8 + nt0 + n) * 64 + L) * 8];
            acc[0][n] = __builtin_amdgcn_mfma_f32_16x16x32_bf16(ah0, bh, acc[0][n], 0, 0, 0);
            acc[1][n] = __builtin_amdgcn_mfma_f32_16x16x32_bf16(ah1, bh, acc[1][n], 0, 0, 0);
        }
    }
}

__device__ __forceinline__ void gemm_lds(
    const unsigned short* Aph_,
    const unsigned short* __restrict__ Whi_g,
    const float* __restrict__ bias, int tid, f32x4 acc[2][4]) {
    const int L = tid & 63;
    const int w = tid >> 6;
    const int mt0 = (w >> 1) * 2;
    const int nt0 = (w & 1) * 4;
    const int lan15 = L & 15;
#pragma unroll
    for (int n = 0; n < 4; n++) {
        float b = bias[(nt0 + n) * 16 + lan15];
        f32x4 bv = {b, b, b, b};
        acc[0][n] = bv;
        acc[1][n] = bv;
    }
#pragma unroll
    for (int kb = 0; kb < 4; kb++) {
        short8 ah0 = *(const short8*)&Aph_[(((mt0 + 0) * 4 + kb) * 64 + L) * 8];
        short8 ah1 = *(const short8*)&Aph_[(((mt0 + 1) * 4 + kb) * 64 + L) * 8];
#pragma unroll
        for (int n = 0; n < 4; n++) {
            short8 bh = *(const short8*)&Whi_g[((kb * 8 + nt0 + n) * 64 + L) * 8];
            acc[0][n] = __builtin_amdgcn_mfma_f32_16x16x32_bf16(ah0, bh, acc[0][n], 0, 0, 0);
            acc[1][n] = __builtin_amdgcn_mfma_f32_16x16x32_bf16(ah1, bh, acc[1][n], 0, 0, 0);
        }
    }
}

template <int FC>
__device__ __forceinline__ void mlp_body(
    const unsigned short* __restrict__ zb,
    const unsigned short* __restrict__ Wahp,
    const unsigned short* __restrict__ Wbhp,
    const float* __restrict__ ba, const float* __restrict__ bb,
    unsigned short* __restrict__ hout,
    const unsigned short* __restrict__ fcWph,
    const float* __restrict__ fcb, float* __restrict__ out) {
    __shared__ unsigned short Aph[8192];   // 16 KB: packed t (bf16)

    const int tid = threadIdx.x;
    const int L = tid & 63;
    const int w = tid >> 6;
    const int mt0 = (w >> 1) * 2;
    const int nt0 = (w & 1) * 4;
    const int lan15 = L & 15;
    const int quad = L >> 4;
    // MLP_GRID = 1563: q = 195, r = 3 (XCD-affinity matches agg_k's ranges)
    const int blk = xcd_swz(blockIdx.x, MLP_GRID / NXCD, MLP_GRID % NXCD);
    const size_t node_base = (size_t)blk * 64;

    // ---- GEMM1: t = ELU(z @ Wa + ba), A straight from global z rows ----
    {
        f32x4 acc[2][4];
        gemm1_g(zb + node_base * HID, Wahp, ba, tid, acc);
        // repack t (bf16) into A-frag LDS; writes are wave-disjoint
#pragma unroll
        for (int i = 0; i < 2; i++) {
#pragma unroll
            for (int n = 0; n < 4; n++) {
                int kdim = (nt0 + n) * 16 + lan15;
                int kb2 = kdim >> 5;
                int q2 = (kdim & 31) >> 3;
                int j2 = kdim & 7;
#pragma unroll
                for (int r = 0; r < 4; r++) {
                    float v = elu(acc[i][n][r]);
                    int mrow = quad * 4 + r;
                    int idx = (((mt0 + i) * 4 + kb2) * 64 + (mrow + 16 * q2)) * 8 + j2;
                    Aph[idx] = f2bf(v);
                }
            }
        }
    }
    __syncthreads();

    // ---- GEMM2: h = ELU(t @ Wb + bb) ----
    {
        f32x4 acc[2][4];
        gemm_lds(Aph, Wbhp, bb, tid, acc);
        if (FC == 0) {
#pragma unroll
            for (int i = 0; i < 2; i++) {
#pragma unroll
                for (int n = 0; n < 4; n++) {
                    int ncol = (nt0 + n) * 16 + lan15;
#pragma unroll
                    for (int r = 0; r < 4; r++) {
                        int mrow = (mt0 + i) * 16 + quad * 4 + r;
                        hout[(node_base + mrow) * HID + ncol] = f2bf(elu(acc[i][n][r]));
                    }
                }
            }
        } else {
            // repack h (bf16, identical rounding to stored-h path) for FC
            __syncthreads();
#pragma unroll
            for (int i = 0; i < 2; i++) {
#pragma unroll
                for (int n = 0; n < 4; n++) {
                    int kdim = (nt0 + n) * 16 + lan15;
                    int kb2 = kdim >> 5;
                    int q2 = (kdim & 31) >> 3;
                    int j2 = kdim & 7;
#pragma unroll
                    for (int r = 0; r < 4; r++) {
                        float v = elu(acc[i][n][r]);
                        int mrow = quad * 4 + r;
                        int idx = (((mt0 + i) * 4 + kb2) * 64 + (mrow + 16 * q2)) * 8 + j2;
                        Aph[idx] = f2bf(v);
                    }
                }
            }
            __syncthreads();
            // FC: waves 0 and 2 handle their 2 M-tiles vs N-tile 0
            if ((w & 1) == 0) {
#pragma unroll
                for (int i = 0; i < 2; i++) {
                    int mt = mt0 + i;
                    float b = (lan15 < N_CLASS) ? fcb[lan15] : 0.f;
                    f32x4 acc2 = {b, b, b, b};
#pragma unroll
                    for (int kb = 0; kb < 4; kb++) {
                        short8 a = *(const short8*)&Aph[((mt * 4 + kb) * 64 + L) * 8];
                        short8 bh = *(const short8*)&fcWph[(kb * 64 + L) * 8];
                        acc2 = __builtin_amdgcn_mfma_f32_16x16x32_bf16(a, bh, acc2, 0, 0, 0);
                    }
#pragma unroll
                    for (int r = 0; r < 4; r++) {
                        size_t node = node_base + mt * 16 + quad * 4 + r;
                        if (node < N_NODES && lan15 < N_CLASS)
                            out[node * N_CLASS + lan15] = acc2[r];
                    }
                }
            }
        }
    }
}

__global__ __launch_bounds__(256) void mlp2_k(
    const unsigned short* __restrict__ zb,
    const unsigned short* __restrict__ Wahp,
    const unsigned short* __restrict__ Wbhp,
    const float* __restrict__ ba, const float* __restrict__ bb,
    unsigned short* __restrict__ hout) {
    mlp_body<0>(zb, Wahp, Wbhp, ba, bb, hout, nullptr, nullptr, nullptr);
}

__global__ __launch_bounds__(256) void mlp3_k(
    const unsigned short* __restrict__ zb,
    const unsigned short* __restrict__ Wahp,
    const unsigned short* __restrict__ Wbhp,
    const float* __restrict__ ba, const float* __restrict__ bb,
    const unsigned short* __restrict__ fcWph,
    const float* __restrict__ fcb, float* __restrict__ out) {
    mlp_body<1>(zb, Wahp, Wbhp, ba, bb, nullptr, fcWph, fcb, out);
}

// ---------------------------------------------------------------------------

extern "C" void kernel_launch(void* const* d_in, const int* in_sizes, int n_in,
                              void* d_out, int out_size, void* d_ws, size_t ws_size,
                              hipStream_t stream) {
    const float* x = (const float*)d_in[0];
    const int* ei = (const int*)d_in[1];  // [2][E]
    // d_in[2] = edge_weight (unused by the reference forward)
    const float* Wa = (const float*)d_in[3];   // [3][128][128]
    const float* ba = (const float*)d_in[4];   // [3][128]
    const float* Wb = (const float*)d_in[5];
    const float* bb = (const float*)d_in[6];
    const float* fcW = (const float*)d_in[7];  // [128][10]
    const float* fcb = (const float*)d_in[8];  // [10]
    float* out = (float*)d_out;

    const int* src = ei;
    const int* dst = ei + N_EDGES;

    // workspace carve
    char* w = (char*)d_ws;
    unsigned short* zb = (unsigned short*)w; w += (size_t)N_PAD * HID * 2;  // bf16 z
    unsigned short* hb = (unsigned short*)w; w += (size_t)N_PAD * HID * 2;  // bf16 h
    int* row_ptr = (int*)w;  w += ((size_t)N_NODES + 8) * 4;
    int* gcnt = (int*)w;     w += (size_t)NRG * GSTRIDE * 4;   // 64 KB padded
    int* col = (int*)w;      w += (size_t)N_EDGES * 4;
    unsigned short* Whp = (unsigned short*)w; w += 6 * 16384 * 2;
    unsigned short* fcWph = (unsigned short*)w; w += 2048 * 2;
    unsigned* gbuf = (unsigned*)w; w += (size_t)NRG * PCAP * 4;  // 8 MB

    // ---- setup: partition + cast + weight pack (one fused kernel) ----
    hipMemsetAsync(gcnt, 0, (size_t)NRG * GSTRIDE * 4, stream);
    const int SETUP_BLOCKS = P_BLOCKS + CAST_BLOCKS + WSPLIT_BLOCKS + 1;
    setup_k<<<SETUP_BLOCKS, 256, 0, stream>>>(src, dst, gcnt, gbuf, x, hb,
                                              Wa, Wb, Whp, fcW, fcWph, row_ptr);
    // ---- counting sort -> CSR ----
    csort_k<<<NRG, 256, 0, stream>>>(gbuf, gcnt, row_ptr, col);

    // ---- layer 1 ----
    agg_k<<<AGG_GRID, 256, 0, stream>>>(hb, row_ptr, col, zb);
    mlp2_k<<<MLP_GRID, 256, 0, stream>>>(zb, Whp, Whp + 16384, ba, bb, hb);
    // ---- layer 2 ----
    agg_k<<<AGG_GRID, 256, 0, stream>>>(hb, row_ptr, col, zb);
    mlp2_k<<<MLP_GRID, 256, 0, stream>>>(zb, Whp + 2 * 16384, Whp + 3 * 16384,
                                         ba + 128, bb + 128, hb);
    // ---- layer 3: MLP + fused final FC ----
    agg_k<<<AGG_GRID, 256, 0, stream>>>(hb, row_ptr, col, zb);
    mlp3_k<<<MLP_GRID, 256, 0, stream>>>(zb, Whp + 4 * 16384, Whp + 5 * 16384,
                                         ba + 256, bb + 256,
                                         fcWph, fcb, out);
}